// Round 4
// baseline (1554.286 us; speedup 1.0000x reference)
//
#include <hip/hip_runtime.h>
#include <math.h>

#define BB 4
#define CC 256
#define OO 256
#define HH 96
#define WW 96
#define HW (HH*WW)          // 9216
#define HIDN 18
#define EPS 1e-5f

__device__ __forceinline__ float sigmoidf_(float x) {
    return __builtin_amdgcn_rcpf(1.0f + __expf(-x));
}
__device__ __forceinline__ float siluf_(float x) { return x * sigmoidf_(x); }

// ---------------------------------------------------------------------------
// Kernel 1: per-(b,c) fused gate + depthwise 3x3 experts + InstanceNorm + SiLU
//           + gated weighted sum over experts  -> moe[b][c][h][w]
// ---------------------------------------------------------------------------
__global__ __launch_bounds__(256)
void k_moe(const float* __restrict__ x,
           const float* __restrict__ w_expert,
           const float* __restrict__ w_g1, const float* __restrict__ b_g1,
           const float* __restrict__ w_g2, const float* __restrict__ b_g2,
           float* __restrict__ moe)
{
    __shared__ float tile[98 * 98];      // 38.4 KB, zero halo
    __shared__ float wexp[81];
    __shared__ float pool[9];
    __shared__ float hbuf[HIDN];
    __shared__ float wgt[9];
    __shared__ float stat[18];
    __shared__ float mu_s[9], rstd_s[9];

    const int bc  = blockIdx.x;
    const int c   = bc & (CC - 1);
    const int tid = threadIdx.x;

    for (int i = tid; i < 98 * 98; i += 256) tile[i] = 0.0f;
    if (tid < 18) stat[tid] = 0.0f;
    if (tid < 9)  pool[tid] = 0.0f;
    if (tid < 81) wexp[tid] = w_expert[c * 81 + tid];
    __syncthreads();

    // load x plane (float4) into interior
    const float4* xp4 = (const float4*)(x + (size_t)bc * HW);
    for (int idx = tid; idx < HW / 4; idx += 256) {      // 9 iters
        int r = idx / 24, q = idx - r * 24;
        float4 v = xp4[idx];
        float* t = &tile[(r + 1) * 98 + q * 4 + 1];
        t[0] = v.x; t[1] = v.y; t[2] = v.z; t[3] = v.w;
    }
    __syncthreads();

    // pooled 3x3 block sums (regions of 32x32)
    for (int r = 0; r < 9; ++r) {
        const int i0 = (r / 3) * 32, j0 = (r % 3) * 32;
        float s = 0.0f;
        for (int idx = tid; idx < 1024; idx += 256) {
            int rr = idx >> 5, cc2 = idx & 31;
            s += tile[(i0 + rr + 1) * 98 + (j0 + cc2 + 1)];
        }
        #pragma unroll
        for (int off = 1; off < 64; off <<= 1) s += __shfl_xor(s, off, 64);
        if ((tid & 63) == 0) atomicAdd(&pool[r], s);
    }
    __syncthreads();

    // gate MLP: 9 -> 18 (SiLU) -> 9 (sigmoid)
    if (tid < HIDN) {
        float acc = b_g1[tid];
        #pragma unroll
        for (int j = 0; j < 9; ++j)
            acc += (pool[j] * (1.0f / 1024.0f)) * w_g1[tid * 9 + j];
        hbuf[tid] = siluf_(acc);
    }
    __syncthreads();
    if (tid < 9) {
        float acc = b_g2[tid];
        #pragma unroll
        for (int k = 0; k < HIDN; ++k) acc += hbuf[k] * w_g2[tid * HIDN + k];
        wgt[tid] = sigmoidf_(acc);
    }
    __syncthreads();

    float wre[81];
    #pragma unroll
    for (int i = 0; i < 81; ++i) wre[i] = wexp[i];

    // pass 1: conv -> per-expert sum / sumsq
    float sum[9], sq[9];
    #pragma unroll
    for (int a = 0; a < 9; ++a) { sum[a] = 0.0f; sq[a] = 0.0f; }

    for (int i = tid; i < HW; i += 256) {
        int r = i / 96, col = i - r * 96;
        const float* bp = &tile[r * 98 + col];
        float n0 = bp[0],   n1 = bp[1],   n2 = bp[2];
        float n3 = bp[98],  n4 = bp[99],  n5 = bp[100];
        float n6 = bp[196], n7 = bp[197], n8 = bp[198];
        #pragma unroll
        for (int a = 0; a < 9; ++a) {
            float v = n0 * wre[a*9+0] + n1 * wre[a*9+1] + n2 * wre[a*9+2]
                    + n3 * wre[a*9+3] + n4 * wre[a*9+4] + n5 * wre[a*9+5]
                    + n6 * wre[a*9+6] + n7 * wre[a*9+7] + n8 * wre[a*9+8];
            sum[a] += v;
            sq[a]  = fmaf(v, v, sq[a]);
        }
    }
    #pragma unroll
    for (int a = 0; a < 9; ++a) {
        float s = sum[a], q = sq[a];
        #pragma unroll
        for (int off = 1; off < 64; off <<= 1) {
            s += __shfl_xor(s, off, 64);
            q += __shfl_xor(q, off, 64);
        }
        if ((tid & 63) == 0) { atomicAdd(&stat[a], s); atomicAdd(&stat[9 + a], q); }
    }
    __syncthreads();
    if (tid < 9) {
        float m = stat[tid] * (1.0f / HW);
        float v = stat[9 + tid] * (1.0f / HW) - m * m;
        mu_s[tid]   = m;
        rstd_s[tid] = rsqrtf(v + EPS);
    }
    __syncthreads();

    float ms_r[9], rs_r[9], wg_r[9];
    #pragma unroll
    for (int a = 0; a < 9; ++a) {
        rs_r[a] = rstd_s[a];
        ms_r[a] = mu_s[a] * rs_r[a];
        wg_r[a] = wgt[a];
    }

    // pass 2: conv -> IN -> SiLU -> gated sum
    float* mpn = moe + (size_t)bc * HW;
    for (int i = tid; i < HW; i += 256) {
        int r = i / 96, col = i - r * 96;
        const float* bp = &tile[r * 98 + col];
        float n0 = bp[0],   n1 = bp[1],   n2 = bp[2];
        float n3 = bp[98],  n4 = bp[99],  n5 = bp[100];
        float n6 = bp[196], n7 = bp[197], n8 = bp[198];
        float acc = 0.0f;
        #pragma unroll
        for (int a = 0; a < 9; ++a) {
            float v = n0 * wre[a*9+0] + n1 * wre[a*9+1] + n2 * wre[a*9+2]
                    + n3 * wre[a*9+3] + n4 * wre[a*9+4] + n5 * wre[a*9+5]
                    + n6 * wre[a*9+6] + n7 * wre[a*9+7] + n8 * wre[a*9+8];
            float t = fmaf(v, rs_r[a], -ms_r[a]);
            acc = fmaf(wg_r[a], t * sigmoidf_(t), acc);
        }
        mpn[i] = acc;
    }
}

// ---------------------------------------------------------------------------
// Kernel 2: z = wproj x moe (fp32), tile 64o x 128p x 32c, reg-prefetch
//           + per-o BN partial sum/sumsq
// ---------------------------------------------------------------------------
#define OT 64
#define PT 128
#define CKK 32

#define FMA4(A, S, M) { A.x = fmaf(S, M.x, A.x); A.y = fmaf(S, M.y, A.y); \
                        A.z = fmaf(S, M.z, A.z); A.w = fmaf(S, M.w, A.w); }

__global__ __launch_bounds__(256, 4)
void k_gemm(const float* __restrict__ moe, const float* __restrict__ wproj,
            float* __restrict__ z, float* __restrict__ stats)
{
    __shared__ float wl[CKK][OT + 4];   // [c][o], 8.7 KB
    __shared__ float ml[CKK][PT];       // [c][p], 16 KB

    const int tid = threadIdx.x;
    const int to  = tid >> 5;           // 0..7  -> o octet
    const int tp  = tid & 31;           // 0..31 -> p quad
    const int p0  = blockIdx.x * PT;
    const int o0  = blockIdx.y * OT;
    const int b   = blockIdx.z;

    // staging coords
    const int wr = tid >> 3;            // 0..31 (o row; +32 for 2nd load)
    const int wj = (tid & 7) * 4;       // c quad offset
    const int mr = tid >> 5;            // 0..7  (c row; +8 per i)
    const int mq = (tid & 31) * 4;      // p quad offset

    const float* wg0 = wproj + (size_t)(o0 + wr) * CC + wj;
    const float* wg1 = wproj + (size_t)(o0 + wr + 32) * CC + wj;
    const float* mg  = moe + ((size_t)b * CC + mr) * HW + p0 + mq;

    float4 acc[8];
    #pragma unroll
    for (int i = 0; i < 8; ++i) acc[i] = make_float4(0.f, 0.f, 0.f, 0.f);

    float4 rw0, rw1, rm[4];

    // stage tile 0 -> regs -> LDS
    rw0 = *(const float4*)wg0;
    rw1 = *(const float4*)wg1;
    #pragma unroll
    for (int i = 0; i < 4; ++i) rm[i] = *(const float4*)(mg + (size_t)i * 8 * HW);

    wl[wj+0][wr] = rw0.x; wl[wj+1][wr] = rw0.y; wl[wj+2][wr] = rw0.z; wl[wj+3][wr] = rw0.w;
    wl[wj+0][wr+32] = rw1.x; wl[wj+1][wr+32] = rw1.y; wl[wj+2][wr+32] = rw1.z; wl[wj+3][wr+32] = rw1.w;
    #pragma unroll
    for (int i = 0; i < 4; ++i) *(float4*)&ml[mr + 8*i][mq] = rm[i];

    #pragma unroll 1
    for (int kt = 0; kt < CC / CKK; ++kt) {
        __syncthreads();                       // staged tile visible
        if (kt < CC / CKK - 1) {               // prefetch next tile into regs
            const float* w0n = wg0 + (kt + 1) * CKK;
            const float* w1n = wg1 + (kt + 1) * CKK;
            const float* mgn = mg + (size_t)(kt + 1) * CKK * HW;
            rw0 = *(const float4*)w0n;
            rw1 = *(const float4*)w1n;
            #pragma unroll
            for (int i = 0; i < 4; ++i) rm[i] = *(const float4*)(mgn + (size_t)i * 8 * HW);
        }
        #pragma unroll
        for (int cc = 0; cc < CKK; ++cc) {     // compute current tile
            float4 m  = *(const float4*)&ml[cc][tp * 4];
            float4 wa = *(const float4*)&wl[cc][to * 8];
            float4 wb = *(const float4*)&wl[cc][to * 8 + 4];
            FMA4(acc[0], wa.x, m); FMA4(acc[1], wa.y, m);
            FMA4(acc[2], wa.z, m); FMA4(acc[3], wa.w, m);
            FMA4(acc[4], wb.x, m); FMA4(acc[5], wb.y, m);
            FMA4(acc[6], wb.z, m); FMA4(acc[7], wb.w, m);
        }
        __syncthreads();                       // all reads done
        if (kt < CC / CKK - 1) {               // write prefetched tile
            wl[wj+0][wr] = rw0.x; wl[wj+1][wr] = rw0.y; wl[wj+2][wr] = rw0.z; wl[wj+3][wr] = rw0.w;
            wl[wj+0][wr+32] = rw1.x; wl[wj+1][wr+32] = rw1.y; wl[wj+2][wr+32] = rw1.z; wl[wj+3][wr+32] = rw1.w;
            #pragma unroll
            for (int i = 0; i < 4; ++i) *(float4*)&ml[mr + 8*i][mq] = rm[i];
        }
    }

    // epilogue: z write + BN partial stats
    #pragma unroll
    for (int oi = 0; oi < 8; ++oi) {
        const int og = o0 + to * 8 + oi;
        *(float4*)(z + ((size_t)b * OO + og) * HW + p0 + tp * 4) = acc[oi];
        float s = acc[oi].x + acc[oi].y + acc[oi].z + acc[oi].w;
        float q = fmaf(acc[oi].x, acc[oi].x, fmaf(acc[oi].y, acc[oi].y,
                  fmaf(acc[oi].z, acc[oi].z, acc[oi].w * acc[oi].w)));
        #pragma unroll
        for (int off = 1; off < 32; off <<= 1) {   // reduce within 32-lane half
            s += __shfl_xor(s, off, 64);
            q += __shfl_xor(q, off, 64);
        }
        if (tp == 0) {
            atomicAdd(&stats[og], s);
            atomicAdd(&stats[OO + og], q);
        }
    }
}

// ---------------------------------------------------------------------------
// Kernel 3: BatchNorm + affine + SiLU; block = one 256-f4 chunk of one (b,o)
// ---------------------------------------------------------------------------
__global__ __launch_bounds__(256)
void k_bnsilu(const float* __restrict__ z, const float* __restrict__ stats,
              const float* __restrict__ gamma, const float* __restrict__ beta,
              float* __restrict__ out)
{
    const int o = blockIdx.y;
    const int b = blockIdx.z;
    const float invn = 1.0f / (float)(BB * HW);
    const float m  = stats[o] * invn;
    const float vv = fmaf(-m, m, stats[OO + o] * invn);
    const float rs = rsqrtf(vv + EPS);
    const float g  = gamma[o] * rs;
    const float bb = fmaf(-m, g, beta[o]);

    const size_t base = ((size_t)b * OO + o) * HW;
    const int i = (blockIdx.x * 256 + threadIdx.x) * 4;   // gridDim.x = HW/4/256 = 9
    float4 v = *(const float4*)(z + base + i);
    v.x = siluf_(fmaf(v.x, g, bb));
    v.y = siluf_(fmaf(v.y, g, bb));
    v.z = siluf_(fmaf(v.z, g, bb));
    v.w = siluf_(fmaf(v.w, g, bb));
    *(float4*)(out + base + i) = v;
}

// ---------------------------------------------------------------------------
extern "C" void kernel_launch(void* const* d_in, const int* in_sizes, int n_in,
                              void* d_out, int out_size, void* d_ws, size_t ws_size,
                              hipStream_t stream)
{
    const float* x        = (const float*)d_in[0];
    const float* w_expert = (const float*)d_in[1];
    const float* w_g1     = (const float*)d_in[2];
    const float* b_g1     = (const float*)d_in[3];
    const float* w_g2     = (const float*)d_in[4];
    const float* b_g2     = (const float*)d_in[5];
    const float* w_proj   = (const float*)d_in[6];
    const float* bn_g     = (const float*)d_in[7];
    const float* bn_b     = (const float*)d_in[8];
    float* out = (float*)d_out;

    float* z     = (float*)d_ws;                    // B*O*HW floats (37.7 MB)
    float* stats = z + (size_t)BB * OO * HW;        // 2*O floats
    float* moe   = out;                             // reuse d_out as scratch

    hipMemsetAsync(stats, 0, 2 * OO * sizeof(float), stream);

    k_moe<<<BB * CC, 256, 0, stream>>>(x, w_expert, w_g1, b_g1, w_g2, b_g2, moe);
    k_gemm<<<dim3(HW / PT, OO / OT, BB), 256, 0, stream>>>(moe, w_proj, z, stats);
    k_bnsilu<<<dim3(HW / 4 / 256, OO, BB), 256, 0, stream>>>(z, stats, bn_g, bn_b, out);
}

// Round 7
// 363.523 us; speedup vs baseline: 4.2756x; 4.2756x over previous
//
#include <hip/hip_runtime.h>
#include <math.h>

#define BB 4
#define CC 256
#define OO 256
#define HH 96
#define WW 96
#define HW (HH*WW)          // 9216
#define HIDN 18
#define EPS 1e-5f

__device__ __forceinline__ float sigmoidf_(float x) {
    return __builtin_amdgcn_rcpf(1.0f + __expf(-x));
}
__device__ __forceinline__ float siluf_(float x) { return x * sigmoidf_(x); }

// ---------------------------------------------------------------------------
// Kernel 1: per-(b,c) fused gate + depthwise 3x3 experts + InstanceNorm + SiLU
//           + gated weighted sum over experts  -> moe[b][c][h][w]
// ---------------------------------------------------------------------------
__global__ __launch_bounds__(256)
void k_moe(const float* __restrict__ x,
           const float* __restrict__ w_expert,
           const float* __restrict__ w_g1, const float* __restrict__ b_g1,
           const float* __restrict__ w_g2, const float* __restrict__ b_g2,
           float* __restrict__ moe)
{
    __shared__ float tile[98 * 98];      // 38.4 KB, zero halo
    __shared__ float wexp[81];
    __shared__ float pool[9];
    __shared__ float hbuf[HIDN];
    __shared__ float wgt[9];
    __shared__ float stat[18];
    __shared__ float mu_s[9], rstd_s[9];

    const int bc  = blockIdx.x;
    const int c   = bc & (CC - 1);
    const int tid = threadIdx.x;

    for (int i = tid; i < 98 * 98; i += 256) tile[i] = 0.0f;
    if (tid < 18) stat[tid] = 0.0f;
    if (tid < 9)  pool[tid] = 0.0f;
    if (tid < 81) wexp[tid] = w_expert[c * 81 + tid];
    __syncthreads();

    // load x plane (float4) into interior
    const float4* xp4 = (const float4*)(x + (size_t)bc * HW);
    for (int idx = tid; idx < HW / 4; idx += 256) {      // 9 iters
        int r = idx / 24, q = idx - r * 24;
        float4 v = xp4[idx];
        float* t = &tile[(r + 1) * 98 + q * 4 + 1];
        t[0] = v.x; t[1] = v.y; t[2] = v.z; t[3] = v.w;
    }
    __syncthreads();

    // pooled 3x3 block sums (regions of 32x32)
    for (int r = 0; r < 9; ++r) {
        const int i0 = (r / 3) * 32, j0 = (r % 3) * 32;
        float s = 0.0f;
        for (int idx = tid; idx < 1024; idx += 256) {
            int rr = idx >> 5, cc2 = idx & 31;
            s += tile[(i0 + rr + 1) * 98 + (j0 + cc2 + 1)];
        }
        #pragma unroll
        for (int off = 1; off < 64; off <<= 1) s += __shfl_xor(s, off, 64);
        if ((tid & 63) == 0) atomicAdd(&pool[r], s);
    }
    __syncthreads();

    // gate MLP: 9 -> 18 (SiLU) -> 9 (sigmoid)
    if (tid < HIDN) {
        float acc = b_g1[tid];
        #pragma unroll
        for (int j = 0; j < 9; ++j)
            acc += (pool[j] * (1.0f / 1024.0f)) * w_g1[tid * 9 + j];
        hbuf[tid] = siluf_(acc);
    }
    __syncthreads();
    if (tid < 9) {
        float acc = b_g2[tid];
        #pragma unroll
        for (int k = 0; k < HIDN; ++k) acc += hbuf[k] * w_g2[tid * HIDN + k];
        wgt[tid] = sigmoidf_(acc);
    }
    __syncthreads();

    float wre[81];
    #pragma unroll
    for (int i = 0; i < 81; ++i) wre[i] = wexp[i];

    // pass 1: conv -> per-expert sum / sumsq
    float sum[9], sq[9];
    #pragma unroll
    for (int a = 0; a < 9; ++a) { sum[a] = 0.0f; sq[a] = 0.0f; }

    for (int i = tid; i < HW; i += 256) {
        int r = i / 96, col = i - r * 96;
        const float* bp = &tile[r * 98 + col];
        float n0 = bp[0],   n1 = bp[1],   n2 = bp[2];
        float n3 = bp[98],  n4 = bp[99],  n5 = bp[100];
        float n6 = bp[196], n7 = bp[197], n8 = bp[198];
        #pragma unroll
        for (int a = 0; a < 9; ++a) {
            float v = n0 * wre[a*9+0] + n1 * wre[a*9+1] + n2 * wre[a*9+2]
                    + n3 * wre[a*9+3] + n4 * wre[a*9+4] + n5 * wre[a*9+5]
                    + n6 * wre[a*9+6] + n7 * wre[a*9+7] + n8 * wre[a*9+8];
            sum[a] += v;
            sq[a]  = fmaf(v, v, sq[a]);
        }
    }
    #pragma unroll
    for (int a = 0; a < 9; ++a) {
        float s = sum[a], q = sq[a];
        #pragma unroll
        for (int off = 1; off < 64; off <<= 1) {
            s += __shfl_xor(s, off, 64);
            q += __shfl_xor(q, off, 64);
        }
        if ((tid & 63) == 0) { atomicAdd(&stat[a], s); atomicAdd(&stat[9 + a], q); }
    }
    __syncthreads();
    if (tid < 9) {
        float m = stat[tid] * (1.0f / HW);
        float v = stat[9 + tid] * (1.0f / HW) - m * m;
        mu_s[tid]   = m;
        rstd_s[tid] = rsqrtf(v + EPS);
    }
    __syncthreads();

    float ms_r[9], rs_r[9], wg_r[9];
    #pragma unroll
    for (int a = 0; a < 9; ++a) {
        rs_r[a] = rstd_s[a];
        ms_r[a] = mu_s[a] * rs_r[a];
        wg_r[a] = wgt[a];
    }

    // pass 2: conv -> IN -> SiLU -> gated sum
    float* mpn = moe + (size_t)bc * HW;
    for (int i = tid; i < HW; i += 256) {
        int r = i / 96, col = i - r * 96;
        const float* bp = &tile[r * 98 + col];
        float n0 = bp[0],   n1 = bp[1],   n2 = bp[2];
        float n3 = bp[98],  n4 = bp[99],  n5 = bp[100];
        float n6 = bp[196], n7 = bp[197], n8 = bp[198];
        float acc = 0.0f;
        #pragma unroll
        for (int a = 0; a < 9; ++a) {
            float v = n0 * wre[a*9+0] + n1 * wre[a*9+1] + n2 * wre[a*9+2]
                    + n3 * wre[a*9+3] + n4 * wre[a*9+4] + n5 * wre[a*9+5]
                    + n6 * wre[a*9+6] + n7 * wre[a*9+7] + n8 * wre[a*9+8];
            float t = fmaf(v, rs_r[a], -ms_r[a]);
            acc = fmaf(wg_r[a], t * sigmoidf_(t), acc);
        }
        mpn[i] = acc;
    }
}

// ---------------------------------------------------------------------------
// Kernel 2: z = wproj x moe (fp32), tile 64o x 128p x 32c, reg-prefetch
//           + per-o BN partial sum/sumsq
// NOTE: __launch_bounds__(256) ONLY — a min-waves arg of 4 caps VGPR at 64
// and spills the 56+ live accumulator/prefetch VGPRs to scratch (round-4:
// 4.7 GB spill traffic/dispatch, 7x regression).
// ---------------------------------------------------------------------------
#define OT 64
#define PT 128
#define CKK 32

#define FMA4(A, S, M) { A.x = fmaf(S, M.x, A.x); A.y = fmaf(S, M.y, A.y); \
                        A.z = fmaf(S, M.z, A.z); A.w = fmaf(S, M.w, A.w); }

__global__ __launch_bounds__(256)
void k_gemm(const float* __restrict__ moe, const float* __restrict__ wproj,
            float* __restrict__ z, float* __restrict__ stats)
{
    __shared__ float wl[CKK][OT + 4];   // [c][o], 8.7 KB
    __shared__ float ml[CKK][PT];       // [c][p], 16 KB

    const int tid = threadIdx.x;
    const int to  = tid >> 5;           // 0..7  -> o octet
    const int tp  = tid & 31;           // 0..31 -> p quad
    const int p0  = blockIdx.x * PT;
    const int o0  = blockIdx.y * OT;
    const int b   = blockIdx.z;

    // staging coords
    const int wr = tid >> 3;            // 0..31 (o row; +32 for 2nd load)
    const int wj = (tid & 7) * 4;       // c quad offset
    const int mr = tid >> 5;            // 0..7  (c row; +8 per i)
    const int mq = (tid & 31) * 4;      // p quad offset

    const float* wg0 = wproj + (size_t)(o0 + wr) * CC + wj;
    const float* wg1 = wproj + (size_t)(o0 + wr + 32) * CC + wj;
    const float* mg  = moe + ((size_t)b * CC + mr) * HW + p0 + mq;

    float4 acc[8];
    #pragma unroll
    for (int i = 0; i < 8; ++i) acc[i] = make_float4(0.f, 0.f, 0.f, 0.f);

    float4 rw0, rw1, rm[4];

    // stage tile 0 -> regs -> LDS
    rw0 = *(const float4*)wg0;
    rw1 = *(const float4*)wg1;
    #pragma unroll
    for (int i = 0; i < 4; ++i) rm[i] = *(const float4*)(mg + (size_t)i * 8 * HW);

    wl[wj+0][wr] = rw0.x; wl[wj+1][wr] = rw0.y; wl[wj+2][wr] = rw0.z; wl[wj+3][wr] = rw0.w;
    wl[wj+0][wr+32] = rw1.x; wl[wj+1][wr+32] = rw1.y; wl[wj+2][wr+32] = rw1.z; wl[wj+3][wr+32] = rw1.w;
    #pragma unroll
    for (int i = 0; i < 4; ++i) *(float4*)&ml[mr + 8*i][mq] = rm[i];

    #pragma unroll 1
    for (int kt = 0; kt < CC / CKK; ++kt) {
        __syncthreads();                       // staged tile visible
        if (kt < CC / CKK - 1) {               // prefetch next tile into regs
            const float* w0n = wg0 + (kt + 1) * CKK;
            const float* w1n = wg1 + (kt + 1) * CKK;
            const float* mgn = mg + (size_t)(kt + 1) * CKK * HW;
            rw0 = *(const float4*)w0n;
            rw1 = *(const float4*)w1n;
            #pragma unroll
            for (int i = 0; i < 4; ++i) rm[i] = *(const float4*)(mgn + (size_t)i * 8 * HW);
        }
        #pragma unroll
        for (int cc = 0; cc < CKK; ++cc) {     // compute current tile
            float4 m  = *(const float4*)&ml[cc][tp * 4];
            float4 wa = *(const float4*)&wl[cc][to * 8];
            float4 wb = *(const float4*)&wl[cc][to * 8 + 4];
            FMA4(acc[0], wa.x, m); FMA4(acc[1], wa.y, m);
            FMA4(acc[2], wa.z, m); FMA4(acc[3], wa.w, m);
            FMA4(acc[4], wb.x, m); FMA4(acc[5], wb.y, m);
            FMA4(acc[6], wb.z, m); FMA4(acc[7], wb.w, m);
        }
        __syncthreads();                       // all reads done
        if (kt < CC / CKK - 1) {               // write prefetched tile
            wl[wj+0][wr] = rw0.x; wl[wj+1][wr] = rw0.y; wl[wj+2][wr] = rw0.z; wl[wj+3][wr] = rw0.w;
            wl[wj+0][wr+32] = rw1.x; wl[wj+1][wr+32] = rw1.y; wl[wj+2][wr+32] = rw1.z; wl[wj+3][wr+32] = rw1.w;
            #pragma unroll
            for (int i = 0; i < 4; ++i) *(float4*)&ml[mr + 8*i][mq] = rm[i];
        }
    }

    // epilogue: z write + BN partial stats
    #pragma unroll
    for (int oi = 0; oi < 8; ++oi) {
        const int og = o0 + to * 8 + oi;
        *(float4*)(z + ((size_t)b * OO + og) * HW + p0 + tp * 4) = acc[oi];
        float s = acc[oi].x + acc[oi].y + acc[oi].z + acc[oi].w;
        float q = fmaf(acc[oi].x, acc[oi].x, fmaf(acc[oi].y, acc[oi].y,
                  fmaf(acc[oi].z, acc[oi].z, acc[oi].w * acc[oi].w)));
        #pragma unroll
        for (int off = 1; off < 32; off <<= 1) {   // reduce within 32-lane half
            s += __shfl_xor(s, off, 64);
            q += __shfl_xor(q, off, 64);
        }
        if (tp == 0) {
            atomicAdd(&stats[og], s);
            atomicAdd(&stats[OO + og], q);
        }
    }
}

// ---------------------------------------------------------------------------
// Kernel 3: BatchNorm + affine + SiLU; block = one 256-f4 chunk of one (b,o)
// ---------------------------------------------------------------------------
__global__ __launch_bounds__(256)
void k_bnsilu(const float* __restrict__ z, const float* __restrict__ stats,
              const float* __restrict__ gamma, const float* __restrict__ beta,
              float* __restrict__ out)
{
    const int o = blockIdx.y;
    const int b = blockIdx.z;
    const float invn = 1.0f / (float)(BB * HW);
    const float m  = stats[o] * invn;
    const float vv = fmaf(-m, m, stats[OO + o] * invn);
    const float rs = rsqrtf(vv + EPS);
    const float g  = gamma[o] * rs;
    const float bb = fmaf(-m, g, beta[o]);

    const size_t base = ((size_t)b * OO + o) * HW;
    const int i = (blockIdx.x * 256 + threadIdx.x) * 4;   // gridDim.x = HW/4/256 = 9
    float4 v = *(const float4*)(z + base + i);
    v.x = siluf_(fmaf(v.x, g, bb));
    v.y = siluf_(fmaf(v.y, g, bb));
    v.z = siluf_(fmaf(v.z, g, bb));
    v.w = siluf_(fmaf(v.w, g, bb));
    *(float4*)(out + base + i) = v;
}

// ---------------------------------------------------------------------------
extern "C" void kernel_launch(void* const* d_in, const int* in_sizes, int n_in,
                              void* d_out, int out_size, void* d_ws, size_t ws_size,
                              hipStream_t stream)
{
    const float* x        = (const float*)d_in[0];
    const float* w_expert = (const float*)d_in[1];
    const float* w_g1     = (const float*)d_in[2];
    const float* b_g1     = (const float*)d_in[3];
    const float* w_g2     = (const float*)d_in[4];
    const float* b_g2     = (const float*)d_in[5];
    const float* w_proj   = (const float*)d_in[6];
    const float* bn_g     = (const float*)d_in[7];
    const float* bn_b     = (const float*)d_in[8];
    float* out = (float*)d_out;

    float* z     = (float*)d_ws;                    // B*O*HW floats (37.7 MB)
    float* stats = z + (size_t)BB * OO * HW;        // 2*O floats
    float* moe   = out;                             // reuse d_out as scratch

    hipMemsetAsync(stats, 0, 2 * OO * sizeof(float), stream);

    k_moe<<<BB * CC, 256, 0, stream>>>(x, w_expert, w_g1, b_g1, w_g2, b_g2, moe);
    k_gemm<<<dim3(HW / PT, OO / OT, BB), 256, 0, stream>>>(moe, w_proj, z, stats);
    k_bnsilu<<<dim3(HW / 4 / 256, OO, BB), 256, 0, stream>>>(z, stats, bn_g, bn_b, out);
}

// Round 8
// 332.252 us; speedup vs baseline: 4.6780x; 1.0941x over previous
//
#include <hip/hip_runtime.h>
#include <math.h>

#define BB 4
#define CC 256
#define OO 256
#define HH 96
#define WW 96
#define HW (HH*WW)          // 9216
#define HIDN 18
#define EPS 1e-5f
#define TS 100              // k_moe LDS tile row stride (16B-aligns all windows)

__device__ __forceinline__ float sigmoidf_(float x) {
    return __builtin_amdgcn_rcpf(1.0f + __expf(-x));
}
__device__ __forceinline__ float siluf_(float x) { return x * sigmoidf_(x); }

// ---------------------------------------------------------------------------
// Kernel 0: transpose w_proj[o][c] -> wt[c][o] (256 KB) so k_gemm's per-c
// weight octets are contiguous + wave-uniform (scalar-load path).
// ---------------------------------------------------------------------------
__global__ __launch_bounds__(256)
void k_wt(const float* __restrict__ w, float* __restrict__ wt)
{
    const int c = blockIdx.x, o = threadIdx.x;
    wt[c * OO + o] = w[o * CC + c];
}

// ---------------------------------------------------------------------------
// Kernel 1: per-(b,c) fused gate + depthwise 3x3 experts + InstanceNorm + SiLU
//           + gated weighted sum -> moe[b][c][h][w]
// Sliding-window conv: 4-px quad per thread-iter, 6 LDS insts/quad (vs 36
// scalar) — round-7 showed LDS-issue cost dominates.
// ---------------------------------------------------------------------------
__global__ __launch_bounds__(256)
void k_moe(const float* __restrict__ x,
           const float* __restrict__ w_expert,
           const float* __restrict__ w_g1, const float* __restrict__ b_g1,
           const float* __restrict__ w_g2, const float* __restrict__ b_g2,
           float* __restrict__ moe)
{
    __shared__ float tile[98 * TS];      // 39.2 KB, zero halo
    __shared__ float wexp[81];
    __shared__ float pool[9];
    __shared__ float hbuf[HIDN];
    __shared__ float wgt[9];
    __shared__ float stat[18];
    __shared__ float mu_s[9], rstd_s[9];

    const int bc  = blockIdx.x;
    const int c   = bc & (CC - 1);
    const int tid = threadIdx.x;

    // zero only the halo cells actually read (row 0, row 97, col 0, col 97)
    if (tid < 98) { tile[tid] = 0.0f; tile[97 * TS + tid] = 0.0f; }
    if (tid < 96) { tile[(tid + 1) * TS] = 0.0f; tile[(tid + 1) * TS + 97] = 0.0f; }
    if (tid < 18) stat[tid] = 0.0f;
    if (tid < 9)  pool[tid] = 0.0f;
    if (tid < 81) wexp[tid] = w_expert[c * 81 + tid];
    __syncthreads();

    // load x plane (float4) into interior
    const float4* xp4 = (const float4*)(x + (size_t)bc * HW);
    for (int idx = tid; idx < HW / 4; idx += 256) {      // 9 iters
        int r = idx / 24, q = idx - r * 24;
        float4 v = xp4[idx];
        float* t = &tile[(r + 1) * TS + q * 4 + 1];
        t[0] = v.x; t[1] = v.y; t[2] = v.z; t[3] = v.w;
    }
    __syncthreads();

    // pooled 3x3 block sums (regions of 32x32)
    for (int r = 0; r < 9; ++r) {
        const int i0 = (r / 3) * 32, j0 = (r % 3) * 32;
        float s = 0.0f;
        for (int idx = tid; idx < 1024; idx += 256) {
            int rr = idx >> 5, cc2 = idx & 31;
            s += tile[(i0 + rr + 1) * TS + (j0 + cc2 + 1)];
        }
        #pragma unroll
        for (int off = 1; off < 64; off <<= 1) s += __shfl_xor(s, off, 64);
        if ((tid & 63) == 0) atomicAdd(&pool[r], s);
    }
    __syncthreads();

    // gate MLP: 9 -> 18 (SiLU) -> 9 (sigmoid)
    if (tid < HIDN) {
        float acc = b_g1[tid];
        #pragma unroll
        for (int j = 0; j < 9; ++j)
            acc += (pool[j] * (1.0f / 1024.0f)) * w_g1[tid * 9 + j];
        hbuf[tid] = siluf_(acc);
    }
    __syncthreads();
    if (tid < 9) {
        float acc = b_g2[tid];
        #pragma unroll
        for (int k = 0; k < HIDN; ++k) acc += hbuf[k] * w_g2[tid * HIDN + k];
        wgt[tid] = sigmoidf_(acc);
    }
    __syncthreads();

    float wre[81];
    #pragma unroll
    for (int i = 0; i < 81; ++i) wre[i] = wexp[i];

    // ---- pass 1: conv (4-px quads) -> per-expert sum / sumsq ----
    float sum[9], sq[9];
    #pragma unroll
    for (int a = 0; a < 9; ++a) { sum[a] = 0.0f; sq[a] = 0.0f; }

    for (int qi = tid; qi < HW / 4; qi += 256) {         // 9 iters
        int r  = qi / 24;
        int c4 = (qi - r * 24) << 2;
        const float* t0 = &tile[r * TS + c4];            // 16B-aligned
        float4 a0 = *(const float4*)t0;        float2 e0 = *(const float2*)(t0 + 4);
        float4 a1 = *(const float4*)(t0 + TS); float2 e1 = *(const float2*)(t0 + TS + 4);
        float4 a2 = *(const float4*)(t0 + 2*TS); float2 e2 = *(const float2*)(t0 + 2*TS + 4);
        float w0[6] = {a0.x, a0.y, a0.z, a0.w, e0.x, e0.y};
        float w1[6] = {a1.x, a1.y, a1.z, a1.w, e1.x, e1.y};
        float w2[6] = {a2.x, a2.y, a2.z, a2.w, e2.x, e2.y};
        #pragma unroll
        for (int a = 0; a < 9; ++a) {
            const float k0 = wre[a*9+0], k1 = wre[a*9+1], k2 = wre[a*9+2];
            const float k3 = wre[a*9+3], k4 = wre[a*9+4], k5 = wre[a*9+5];
            const float k6 = wre[a*9+6], k7 = wre[a*9+7], k8 = wre[a*9+8];
            #pragma unroll
            for (int j = 0; j < 4; ++j) {
                float v = w0[j] * k0;
                v = fmaf(w0[j+1], k1, v); v = fmaf(w0[j+2], k2, v);
                v = fmaf(w1[j],   k3, v); v = fmaf(w1[j+1], k4, v);
                v = fmaf(w1[j+2], k5, v); v = fmaf(w2[j],   k6, v);
                v = fmaf(w2[j+1], k7, v); v = fmaf(w2[j+2], k8, v);
                sum[a] += v;
                sq[a]   = fmaf(v, v, sq[a]);
            }
        }
    }
    #pragma unroll
    for (int a = 0; a < 9; ++a) {
        float s = sum[a], q = sq[a];
        #pragma unroll
        for (int off = 1; off < 64; off <<= 1) {
            s += __shfl_xor(s, off, 64);
            q += __shfl_xor(q, off, 64);
        }
        if ((tid & 63) == 0) { atomicAdd(&stat[a], s); atomicAdd(&stat[9 + a], q); }
    }
    __syncthreads();
    if (tid < 9) {
        float m = stat[tid] * (1.0f / HW);
        float v = stat[9 + tid] * (1.0f / HW) - m * m;
        mu_s[tid]   = m;
        rstd_s[tid] = rsqrtf(v + EPS);
    }
    __syncthreads();

    float ms_r[9], rs_r[9], wg_r[9];
    #pragma unroll
    for (int a = 0; a < 9; ++a) {
        rs_r[a] = rstd_s[a];
        ms_r[a] = mu_s[a] * rs_r[a];
        wg_r[a] = wgt[a];
    }

    // ---- pass 2: conv -> IN -> SiLU -> gated sum ----
    float* mpn = moe + (size_t)bc * HW;
    for (int qi = tid; qi < HW / 4; qi += 256) {
        int r  = qi / 24;
        int c4 = (qi - r * 24) << 2;
        const float* t0 = &tile[r * TS + c4];
        float4 a0 = *(const float4*)t0;        float2 e0 = *(const float2*)(t0 + 4);
        float4 a1 = *(const float4*)(t0 + TS); float2 e1 = *(const float2*)(t0 + TS + 4);
        float4 a2 = *(const float4*)(t0 + 2*TS); float2 e2 = *(const float2*)(t0 + 2*TS + 4);
        float w0[6] = {a0.x, a0.y, a0.z, a0.w, e0.x, e0.y};
        float w1[6] = {a1.x, a1.y, a1.z, a1.w, e1.x, e1.y};
        float w2[6] = {a2.x, a2.y, a2.z, a2.w, e2.x, e2.y};
        float oq[4] = {0.f, 0.f, 0.f, 0.f};
        #pragma unroll
        for (int a = 0; a < 9; ++a) {
            const float k0 = wre[a*9+0], k1 = wre[a*9+1], k2 = wre[a*9+2];
            const float k3 = wre[a*9+3], k4 = wre[a*9+4], k5 = wre[a*9+5];
            const float k6 = wre[a*9+6], k7 = wre[a*9+7], k8 = wre[a*9+8];
            #pragma unroll
            for (int j = 0; j < 4; ++j) {
                float v = w0[j] * k0;
                v = fmaf(w0[j+1], k1, v); v = fmaf(w0[j+2], k2, v);
                v = fmaf(w1[j],   k3, v); v = fmaf(w1[j+1], k4, v);
                v = fmaf(w1[j+2], k5, v); v = fmaf(w2[j],   k6, v);
                v = fmaf(w2[j+1], k7, v); v = fmaf(w2[j+2], k8, v);
                float t = fmaf(v, rs_r[a], -ms_r[a]);
                oq[j] = fmaf(wg_r[a], t * sigmoidf_(t), oq[j]);
            }
        }
        *(float4*)(mpn + r * 96 + c4) = make_float4(oq[0], oq[1], oq[2], oq[3]);
    }
}

// ---------------------------------------------------------------------------
// Kernel 2 (v3): z = wproj x moe — LDS-FREE. Round-7 counters showed the
// LDS-staged version is ds_read-issue-bound (3 b128 / 32 FMA). Here:
//  - w from wt[c][o] via wave-uniform address (readfirstlane) -> s_load (SMEM)
//  - moe straight from global (L2-resident), dwordx4, unroll-4
//  - no barriers, ~70-100 VGPR -> high occupancy
// Block: 4 waves; wave (wo=wv&1, wp=wv>>1) covers 8 o x 256 p of a
// 16o x 512p block tile. Grid (18, 16, 4) = 1152 blocks.
// ---------------------------------------------------------------------------
#define GOT 16
#define GPT 512

#define FMA4(A, S, M) { A.x = fmaf(S, M.x, A.x); A.y = fmaf(S, M.y, A.y); \
                        A.z = fmaf(S, M.z, A.z); A.w = fmaf(S, M.w, A.w); }

__global__ __launch_bounds__(256)
void k_gemm(const float* __restrict__ moe, const float* __restrict__ wt,
            float* __restrict__ z, float* __restrict__ stats)
{
    const int tid  = threadIdx.x;
    const int wv   = tid >> 6;
    const int lane = tid & 63;
    const int wo   = wv & 1;
    const int wp   = wv >> 1;
    const int b    = blockIdx.z;

    const int obase = blockIdx.y * GOT + wo * 8;
    const int obu   = __builtin_amdgcn_readfirstlane(obase);
    const int pbase = blockIdx.x * GPT + wp * 256 + lane * 4;

    const float* mptr = moe + (size_t)b * CC * HW + pbase;

    float4 acc[8];
    #pragma unroll
    for (int i = 0; i < 8; ++i) acc[i] = make_float4(0.f, 0.f, 0.f, 0.f);

    #pragma unroll 1
    for (int c = 0; c < CC; c += 4) {
        float4 mv[4];
        #pragma unroll
        for (int u = 0; u < 4; ++u)
            mv[u] = *(const float4*)(mptr + (size_t)(c + u) * HW);
        #pragma unroll
        for (int u = 0; u < 4; ++u) {
            const float* wr = wt + (size_t)(c + u) * OO + obu;   // uniform addr
            float4 wa = *(const float4*)wr;
            float4 wb = *(const float4*)(wr + 4);
            FMA4(acc[0], wa.x, mv[u]); FMA4(acc[1], wa.y, mv[u]);
            FMA4(acc[2], wa.z, mv[u]); FMA4(acc[3], wa.w, mv[u]);
            FMA4(acc[4], wb.x, mv[u]); FMA4(acc[5], wb.y, mv[u]);
            FMA4(acc[6], wb.z, mv[u]); FMA4(acc[7], wb.w, mv[u]);
        }
    }

    // epilogue: z write + BN partial stats (full 64-lane reduce, 1 atomic/o)
    #pragma unroll
    for (int oi = 0; oi < 8; ++oi) {
        *(float4*)(z + ((size_t)b * OO + obase + oi) * HW + pbase) = acc[oi];
        float s = acc[oi].x + acc[oi].y + acc[oi].z + acc[oi].w;
        float q = fmaf(acc[oi].x, acc[oi].x, fmaf(acc[oi].y, acc[oi].y,
                  fmaf(acc[oi].z, acc[oi].z, acc[oi].w * acc[oi].w)));
        #pragma unroll
        for (int off = 1; off < 64; off <<= 1) {
            s += __shfl_xor(s, off, 64);
            q += __shfl_xor(q, off, 64);
        }
        if (lane == 0) {
            atomicAdd(&stats[obu + oi], s);
            atomicAdd(&stats[OO + obu + oi], q);
        }
    }
}

// ---------------------------------------------------------------------------
// Kernel 3: BatchNorm + affine + SiLU; block = one 256-f4 chunk of one (b,o)
// ---------------------------------------------------------------------------
__global__ __launch_bounds__(256)
void k_bnsilu(const float* __restrict__ z, const float* __restrict__ stats,
              const float* __restrict__ gamma, const float* __restrict__ beta,
              float* __restrict__ out)
{
    const int o = blockIdx.y;
    const int b = blockIdx.z;
    const float invn = 1.0f / (float)(BB * HW);
    const float m  = stats[o] * invn;
    const float vv = fmaf(-m, m, stats[OO + o] * invn);
    const float rs = rsqrtf(vv + EPS);
    const float g  = gamma[o] * rs;
    const float bb = fmaf(-m, g, beta[o]);

    const size_t base = ((size_t)b * OO + o) * HW;
    const int i = (blockIdx.x * 256 + threadIdx.x) * 4;   // gridDim.x = 9
    float4 v = *(const float4*)(z + base + i);
    v.x = siluf_(fmaf(v.x, g, bb));
    v.y = siluf_(fmaf(v.y, g, bb));
    v.z = siluf_(fmaf(v.z, g, bb));
    v.w = siluf_(fmaf(v.w, g, bb));
    *(float4*)(out + base + i) = v;
}

// ---------------------------------------------------------------------------
extern "C" void kernel_launch(void* const* d_in, const int* in_sizes, int n_in,
                              void* d_out, int out_size, void* d_ws, size_t ws_size,
                              hipStream_t stream)
{
    const float* x        = (const float*)d_in[0];
    const float* w_expert = (const float*)d_in[1];
    const float* w_g1     = (const float*)d_in[2];
    const float* b_g1     = (const float*)d_in[3];
    const float* w_g2     = (const float*)d_in[4];
    const float* b_g2     = (const float*)d_in[5];
    const float* w_proj   = (const float*)d_in[6];
    const float* bn_g     = (const float*)d_in[7];
    const float* bn_b     = (const float*)d_in[8];
    float* out = (float*)d_out;

    float* z     = (float*)d_ws;                    // B*O*HW floats (36 MiB)
    float* stats = z + (size_t)BB * OO * HW;        // 2*O floats
    float* wt    = stats + 2 * OO;                  // 256x256 transposed w
    float* moe   = out;                             // reuse d_out as scratch

    hipMemsetAsync(stats, 0, 2 * OO * sizeof(float), stream);

    k_wt<<<CC, 256, 0, stream>>>(w_proj, wt);
    k_moe<<<BB * CC, 256, 0, stream>>>(x, w_expert, w_g1, b_g1, w_g2, b_g2, moe);
    k_gemm<<<dim3(HW / GPT, OO / GOT, BB), 256, 0, stream>>>(moe, wt, z, stats);
    k_bnsilu<<<dim3(HW / 4 / 256, OO, BB), 256, 0, stream>>>(z, stats, bn_g, bn_b, out);
}

// Round 10
// 286.439 us; speedup vs baseline: 5.4262x; 1.1599x over previous
//
#include <hip/hip_runtime.h>
#include <math.h>

#define BB 4
#define CC 256
#define OO 256
#define HH 96
#define WW 96
#define HW (HH*WW)          // 9216
#define HIDN 18
#define EPS 1e-5f
#define TS 100              // k_moe LDS tile row stride (16B-aligns all windows)

__device__ __forceinline__ float sigmoidf_(float x) {
    return __builtin_amdgcn_rcpf(1.0f + __expf(-x));
}
__device__ __forceinline__ float siluf_(float x) { return x * sigmoidf_(x); }

// ---------------------------------------------------------------------------
// Kernel 0: transpose w_proj[o][c] -> wt[c][o]
// ---------------------------------------------------------------------------
__global__ __launch_bounds__(256)
void k_wt(const float* __restrict__ w, float* __restrict__ wt)
{
    const int c = blockIdx.x, o = threadIdx.x;
    wt[c * OO + o] = w[o * CC + c];
}

// ---------------------------------------------------------------------------
// Kernel 1: per-(b,c) fused gate + depthwise 3x3 experts + InstanceNorm + SiLU
//           + gated weighted sum -> moe[b][c][h][w]
// Expert weights read via BLOCK-UNIFORM global addresses (c*81 + const idx)
// -> s_load/SGPR, freeing ~81 VGPRs (round-8: VGPR=136 capped occupancy at
// 3 waves/SIMD -> 11% occupancy, 39% VALUBusy).
// ---------------------------------------------------------------------------
__global__ __launch_bounds__(256)
void k_moe(const float* __restrict__ x,
           const float* __restrict__ w_expert,
           const float* __restrict__ w_g1, const float* __restrict__ b_g1,
           const float* __restrict__ w_g2, const float* __restrict__ b_g2,
           float* __restrict__ moe)
{
    __shared__ float tile[98 * TS];      // 39.2 KB, zero halo
    __shared__ float pool[9];
    __shared__ float hbuf[HIDN];
    __shared__ float wgt[9];
    __shared__ float stat[18];
    __shared__ float mu_s[9], rstd_s[9];

    const int bc  = blockIdx.x;
    const int c   = bc & (CC - 1);
    const int tid = threadIdx.x;
    const float* __restrict__ we = w_expert + c * 81;   // uniform base

    // zero only the halo cells actually read
    if (tid < 98) { tile[tid] = 0.0f; tile[97 * TS + tid] = 0.0f; }
    if (tid < 96) { tile[(tid + 1) * TS] = 0.0f; tile[(tid + 1) * TS + 97] = 0.0f; }
    if (tid < 18) stat[tid] = 0.0f;
    if (tid < 9)  pool[tid] = 0.0f;
    __syncthreads();

    // load x plane (float4) into interior
    const float4* xp4 = (const float4*)(x + (size_t)bc * HW);
    for (int idx = tid; idx < HW / 4; idx += 256) {      // 9 iters
        int r = idx / 24, q = idx - r * 24;
        float4 v = xp4[idx];
        float* t = &tile[(r + 1) * TS + q * 4 + 1];
        t[0] = v.x; t[1] = v.y; t[2] = v.z; t[3] = v.w;
    }
    __syncthreads();

    // pooled 3x3 block sums (regions of 32x32)
    for (int r = 0; r < 9; ++r) {
        const int i0 = (r / 3) * 32, j0 = (r % 3) * 32;
        float s = 0.0f;
        for (int idx = tid; idx < 1024; idx += 256) {
            int rr = idx >> 5, cc2 = idx & 31;
            s += tile[(i0 + rr + 1) * TS + (j0 + cc2 + 1)];
        }
        #pragma unroll
        for (int off = 1; off < 64; off <<= 1) s += __shfl_xor(s, off, 64);
        if ((tid & 63) == 0) atomicAdd(&pool[r], s);
    }
    __syncthreads();

    // gate MLP: 9 -> 18 (SiLU) -> 9 (sigmoid)
    if (tid < HIDN) {
        float acc = b_g1[tid];
        #pragma unroll
        for (int j = 0; j < 9; ++j)
            acc += (pool[j] * (1.0f / 1024.0f)) * w_g1[tid * 9 + j];
        hbuf[tid] = siluf_(acc);
    }
    __syncthreads();
    if (tid < 9) {
        float acc = b_g2[tid];
        #pragma unroll
        for (int k = 0; k < HIDN; ++k) acc += hbuf[k] * w_g2[tid * HIDN + k];
        wgt[tid] = sigmoidf_(acc);
    }
    __syncthreads();

    // ---- pass 1: conv (4-px quads) -> per-expert sum / sumsq ----
    float sum[9], sq[9];
    #pragma unroll
    for (int a = 0; a < 9; ++a) { sum[a] = 0.0f; sq[a] = 0.0f; }

    for (int qi = tid; qi < HW / 4; qi += 256) {         // 9 iters
        int r  = qi / 24;
        int c4 = (qi - r * 24) << 2;
        const float* t0 = &tile[r * TS + c4];            // 16B-aligned
        float4 a0 = *(const float4*)t0;        float2 e0 = *(const float2*)(t0 + 4);
        float4 a1 = *(const float4*)(t0 + TS); float2 e1 = *(const float2*)(t0 + TS + 4);
        float4 a2 = *(const float4*)(t0 + 2*TS); float2 e2 = *(const float2*)(t0 + 2*TS + 4);
        float w0[6] = {a0.x, a0.y, a0.z, a0.w, e0.x, e0.y};
        float w1[6] = {a1.x, a1.y, a1.z, a1.w, e1.x, e1.y};
        float w2[6] = {a2.x, a2.y, a2.z, a2.w, e2.x, e2.y};
        #pragma unroll
        for (int a = 0; a < 9; ++a) {
            const float k0 = we[a*9+0], k1 = we[a*9+1], k2 = we[a*9+2];
            const float k3 = we[a*9+3], k4 = we[a*9+4], k5 = we[a*9+5];
            const float k6 = we[a*9+6], k7 = we[a*9+7], k8 = we[a*9+8];
            #pragma unroll
            for (int j = 0; j < 4; ++j) {
                float v = w0[j] * k0;
                v = fmaf(w0[j+1], k1, v); v = fmaf(w0[j+2], k2, v);
                v = fmaf(w1[j],   k3, v); v = fmaf(w1[j+1], k4, v);
                v = fmaf(w1[j+2], k5, v); v = fmaf(w2[j],   k6, v);
                v = fmaf(w2[j+1], k7, v); v = fmaf(w2[j+2], k8, v);
                sum[a] += v;
                sq[a]   = fmaf(v, v, sq[a]);
            }
        }
    }
    #pragma unroll
    for (int a = 0; a < 9; ++a) {
        float s = sum[a], q = sq[a];
        #pragma unroll
        for (int off = 1; off < 64; off <<= 1) {
            s += __shfl_xor(s, off, 64);
            q += __shfl_xor(q, off, 64);
        }
        if ((tid & 63) == 0) { atomicAdd(&stat[a], s); atomicAdd(&stat[9 + a], q); }
    }
    __syncthreads();
    if (tid < 9) {
        float m = stat[tid] * (1.0f / HW);
        float v = stat[9 + tid] * (1.0f / HW) - m * m;
        mu_s[tid]   = m;
        rstd_s[tid] = rsqrtf(v + EPS);
    }
    __syncthreads();

    float ms_r[9], rs_r[9], wg_r[9];
    #pragma unroll
    for (int a = 0; a < 9; ++a) {
        rs_r[a] = rstd_s[a];
        ms_r[a] = mu_s[a] * rs_r[a];
        wg_r[a] = wgt[a];
    }

    // ---- pass 2: conv -> IN -> SiLU -> gated sum ----
    float* mpn = moe + (size_t)bc * HW;
    for (int qi = tid; qi < HW / 4; qi += 256) {
        int r  = qi / 24;
        int c4 = (qi - r * 24) << 2;
        const float* t0 = &tile[r * TS + c4];
        float4 a0 = *(const float4*)t0;        float2 e0 = *(const float2*)(t0 + 4);
        float4 a1 = *(const float4*)(t0 + TS); float2 e1 = *(const float2*)(t0 + TS + 4);
        float4 a2 = *(const float4*)(t0 + 2*TS); float2 e2 = *(const float2*)(t0 + 2*TS + 4);
        float w0[6] = {a0.x, a0.y, a0.z, a0.w, e0.x, e0.y};
        float w1[6] = {a1.x, a1.y, a1.z, a1.w, e1.x, e1.y};
        float w2[6] = {a2.x, a2.y, a2.z, a2.w, e2.x, e2.y};
        float oq[4] = {0.f, 0.f, 0.f, 0.f};
        #pragma unroll
        for (int a = 0; a < 9; ++a) {
            const float k0 = we[a*9+0], k1 = we[a*9+1], k2 = we[a*9+2];
            const float k3 = we[a*9+3], k4 = we[a*9+4], k5 = we[a*9+5];
            const float k6 = we[a*9+6], k7 = we[a*9+7], k8 = we[a*9+8];
            #pragma unroll
            for (int j = 0; j < 4; ++j) {
                float v = w0[j] * k0;
                v = fmaf(w0[j+1], k1, v); v = fmaf(w0[j+2], k2, v);
                v = fmaf(w1[j],   k3, v); v = fmaf(w1[j+1], k4, v);
                v = fmaf(w1[j+2], k5, v); v = fmaf(w2[j],   k6, v);
                v = fmaf(w2[j+1], k7, v); v = fmaf(w2[j+2], k8, v);
                float t = fmaf(v, rs_r[a], -ms_r[a]);
                oq[j] = fmaf(wg_r[a], t * sigmoidf_(t), oq[j]);
            }
        }
        *(float4*)(mpn + r * 96 + c4) = make_float4(oq[0], oq[1], oq[2], oq[3]);
    }
}

// ---------------------------------------------------------------------------
// Kernel 2: z = wproj x moe — LDS-free (w via SGPR s_load, moe from global).
// XCD-CLUSTERED 1-D grid: the 16 o-tile blocks sharing one (b,p-tile) get ids
// congruent mod 8 -> same XCD -> the 512KB moe p-slice is re-read from that
// XCD's L2 (34 TB/s) instead of L3/HBM (round-8: 603 MB cross-XCD traffic).
// id(g=b*18+pt, ot) = ((g/8)*16 + ot)*8 + g%8, bijective over 1152.
// ---------------------------------------------------------------------------
#define GOT 16
#define GPT 512

#define FMA4(A, S, M) { A.x = fmaf(S, M.x, A.x); A.y = fmaf(S, M.y, A.y); \
                        A.z = fmaf(S, M.z, A.z); A.w = fmaf(S, M.w, A.w); }

__global__ __launch_bounds__(256)
void k_gemm(const float* __restrict__ moe, const float* __restrict__ wt,
            float* __restrict__ z, float* __restrict__ stats)
{
    const int id   = blockIdx.x;
    const int cls  = id & 7;
    const int m    = id >> 3;
    const int ot   = m & 15;
    const int g    = (m >> 4) * 8 + cls;    // 0..71
    const int b    = g / 18;
    const int pt   = g - b * 18;

    const int tid  = threadIdx.x;
    const int wv   = tid >> 6;
    const int lane = tid & 63;
    const int wo   = wv & 1;
    const int wp   = wv >> 1;

    const int obase = ot * GOT + wo * 8;
    const int obu   = __builtin_amdgcn_readfirstlane(obase);
    const int pbase = pt * GPT + wp * 256 + lane * 4;

    const float* mptr = moe + (size_t)b * CC * HW + pbase;

    float4 acc[8];
    #pragma unroll
    for (int i = 0; i < 8; ++i) acc[i] = make_float4(0.f, 0.f, 0.f, 0.f);

    #pragma unroll 1
    for (int c = 0; c < CC; c += 4) {
        float4 mv[4];
        #pragma unroll
        for (int u = 0; u < 4; ++u)
            mv[u] = *(const float4*)(mptr + (size_t)(c + u) * HW);
        #pragma unroll
        for (int u = 0; u < 4; ++u) {
            const float* wr = wt + (size_t)(c + u) * OO + obu;   // uniform addr
            float4 wa = *(const float4*)wr;
            float4 wb = *(const float4*)(wr + 4);
            FMA4(acc[0], wa.x, mv[u]); FMA4(acc[1], wa.y, mv[u]);
            FMA4(acc[2], wa.z, mv[u]); FMA4(acc[3], wa.w, mv[u]);
            FMA4(acc[4], wb.x, mv[u]); FMA4(acc[5], wb.y, mv[u]);
            FMA4(acc[6], wb.z, mv[u]); FMA4(acc[7], wb.w, mv[u]);
        }
    }

    // epilogue: z write + BN partial stats
    #pragma unroll
    for (int oi = 0; oi < 8; ++oi) {
        *(float4*)(z + ((size_t)b * OO + obase + oi) * HW + pbase) = acc[oi];
        float s = acc[oi].x + acc[oi].y + acc[oi].z + acc[oi].w;
        float q = fmaf(acc[oi].x, acc[oi].x, fmaf(acc[oi].y, acc[oi].y,
                  fmaf(acc[oi].z, acc[oi].z, acc[oi].w * acc[oi].w)));
        #pragma unroll
        for (int off = 1; off < 64; off <<= 1) {
            s += __shfl_xor(s, off, 64);
            q += __shfl_xor(q, off, 64);
        }
        if (lane == 0) {
            atomicAdd(&stats[obu + oi], s);
            atomicAdd(&stats[OO + obu + oi], q);
        }
    }
}

// ---------------------------------------------------------------------------
// Kernel 3: BatchNorm + affine + SiLU; block = one (b,o) plane, 9 f4/thread
// ---------------------------------------------------------------------------
__global__ __launch_bounds__(256)
void k_bnsilu(const float* __restrict__ z, const float* __restrict__ stats,
              const float* __restrict__ gamma, const float* __restrict__ beta,
              float* __restrict__ out)
{
    const int o = blockIdx.y;
    const int b = blockIdx.z;
    const float invn = 1.0f / (float)(BB * HW);
    const float m  = stats[o] * invn;
    const float vv = fmaf(-m, m, stats[OO + o] * invn);
    const float rs = rsqrtf(vv + EPS);
    const float g  = gamma[o] * rs;
    const float bb = fmaf(-m, g, beta[o]);

    const float4* zp = (const float4*)(z + ((size_t)b * OO + o) * HW);
    float4*       op = (float4*)(out + ((size_t)b * OO + o) * HW);
    #pragma unroll
    for (int j = 0; j < 9; ++j) {                 // 2304 f4 = 9 x 256
        const int i = j * 256 + threadIdx.x;
        float4 v = zp[i];
        v.x = siluf_(fmaf(v.x, g, bb));
        v.y = siluf_(fmaf(v.y, g, bb));
        v.z = siluf_(fmaf(v.z, g, bb));
        v.w = siluf_(fmaf(v.w, g, bb));
        op[i] = v;
    }
}

// ---------------------------------------------------------------------------
extern "C" void kernel_launch(void* const* d_in, const int* in_sizes, int n_in,
                              void* d_out, int out_size, void* d_ws, size_t ws_size,
                              hipStream_t stream)
{
    const float* x        = (const float*)d_in[0];
    const float* w_expert = (const float*)d_in[1];
    const float* w_g1     = (const float*)d_in[2];
    const float* b_g1     = (const float*)d_in[3];
    const float* w_g2     = (const float*)d_in[4];
    const float* b_g2     = (const float*)d_in[5];
    const float* w_proj   = (const float*)d_in[6];
    const float* bn_g     = (const float*)d_in[7];
    const float* bn_b     = (const float*)d_in[8];
    float* out = (float*)d_out;

    float* z     = (float*)d_ws;                    // B*O*HW floats (36 MiB)
    float* stats = z + (size_t)BB * OO * HW;        // 2*O floats
    float* wt    = stats + 2 * OO;                  // 256x256 transposed w
    float* moe   = out;                             // reuse d_out as scratch

    hipMemsetAsync(stats, 0, 2 * OO * sizeof(float), stream);

    k_wt<<<CC, 256, 0, stream>>>(w_proj, wt);
    k_moe<<<BB * CC, 256, 0, stream>>>(x, w_expert, w_g1, b_g1, w_g2, b_g2, moe);
    k_gemm<<<BB * (HW / GPT) * (OO / GOT), 256, 0, stream>>>(moe, wt, z, stats);
    k_bnsilu<<<dim3(1, OO, BB), 256, 0, stream>>>(z, stats, bn_g, bn_b, out);
}